// Round 1
// baseline (2974.170 us; speedup 1.0000x reference)
//
#include <hip/hip_runtime.h>
#include <hip/hip_bf16.h>

#define N_NODES 50000
#define N_EDGES 1600000
#define D 128
#define BV 5      // bond vocab
#define NBF 3     // num bond features

// ---------------------------------------------------------------------------
// Kernel 1: per-edge message + scatter-add.
// 32 lanes per edge, float4 per lane (32*4 = 128 = D). 8 edges / 256-thr block.
// Bond embedding table (3*5*128 floats = 7.5 KB) staged in LDS.
// ---------------------------------------------------------------------------
__global__ __launch_bounds__(256) void k_edge(
    const float* __restrict__ x, const int* __restrict__ ea,
    const int* __restrict__ src, const int* __restrict__ dst,
    const float* __restrict__ bemb, float* __restrict__ agg) {
  __shared__ float semb[NBF * BV * D];  // 1920 floats
  for (int i = threadIdx.x; i < NBF * BV * D; i += 256) semb[i] = bemb[i];
  __syncthreads();

  const int e = blockIdx.x * 8 + (threadIdx.x >> 5);  // E % 8 == 0, no guard
  const int col = (threadIdx.x & 31) << 2;

  const int s = src[e];
  const int d = dst[e];
  const int a0 = ea[e * 3 + 0];
  const int a1 = ea[e * 3 + 1];
  const int a2 = ea[e * 3 + 2];

  const float4 e0 = *(const float4*)(semb + a0 * D + col);
  const float4 e1 = *(const float4*)(semb + (BV + a1) * D + col);
  const float4 e2 = *(const float4*)(semb + (2 * BV + a2) * D + col);
  const float4 xv = *(const float4*)(x + (size_t)s * D + col);

  const float m0 = fmaxf(xv.x + e0.x + e1.x + e2.x, 0.f);
  const float m1 = fmaxf(xv.y + e0.y + e1.y + e2.y, 0.f);
  const float m2 = fmaxf(xv.z + e0.z + e1.z + e2.z, 0.f);
  const float m3 = fmaxf(xv.w + e0.w + e1.w + e2.w, 0.f);

  float* p = agg + (size_t)d * D + col;
  atomicAdd(p + 0, m0);
  atomicAdd(p + 1, m1);
  atomicAdd(p + 2, m2);
  atomicAdd(p + 3, m3);
}

// ---------------------------------------------------------------------------
// Kernel 2: h = (1+eps)*x + agg ; h1 = h @ W1 + b1 (in-place over agg buffer);
// fused BN column sum/sumsq accumulation (LDS reduce -> global atomics).
// 32 rows per block; W1 staged in LDS in two 32KB column-halves.
// ---------------------------------------------------------------------------
__global__ __launch_bounds__(256) void k_gemm1(
    const float* __restrict__ x, const float* __restrict__ epsp,
    const float* __restrict__ W1, const float* __restrict__ b1,
    float* hbuf, float* gsum, float* gsumsq) {
  __shared__ float sW[64 * D];   // 32 KB: half of W1, layout [k][64]
  __shared__ float sh[32][D];    // 16 KB
  __shared__ float sb[D];
  __shared__ float ssum[D];
  __shared__ float ssq[D];

  const int tid = threadIdx.x;
  const int row0 = blockIdx.x * 32;
  const float eps1 = 1.0f + epsp[0];

  if (tid < D) { sb[tid] = b1[tid]; ssum[tid] = 0.f; ssq[tid] = 0.f; }

  // stage h rows into LDS: 32 rows * 128 cols = 1024 float4
  for (int i = tid; i < 1024; i += 256) {
    const int r = i >> 5;
    const int c4 = (i & 31) << 2;
    const int gr = row0 + r;
    float4 hv = make_float4(0.f, 0.f, 0.f, 0.f);
    if (gr < N_NODES) {
      const float4 xv = *(const float4*)(x + (size_t)gr * D + c4);
      const float4 av = *(const float4*)(hbuf + (size_t)gr * D + c4);
      hv.x = eps1 * xv.x + av.x;
      hv.y = eps1 * xv.y + av.y;
      hv.z = eps1 * xv.z + av.z;
      hv.w = eps1 * xv.w + av.w;
    }
    *(float4*)(&sh[r][c4]) = hv;
  }

  const int cg = tid & 15;    // 16 col-groups of 4 cols within the 64-col half
  const int rsub = tid >> 4;  // 0..15

  for (int p = 0; p < 2; ++p) {
    __syncthreads();  // staging done (p=0) / previous pass readers done (p=1)
    // load W1 half: cols [p*64, p*64+64), 128*64 floats = 2048 float4
    for (int i = tid; i < 2048; i += 256) {
      const int k = i >> 4;
      const int c4 = (i & 15) << 2;
      *(float4*)(sW + k * 64 + c4) = *(const float4*)(W1 + k * D + p * 64 + c4);
    }
    __syncthreads();

    const int ccol = p * 64 + cg * 4;
    for (int t = 0; t < 2; ++t) {
      const int rr = rsub + t * 16;
      const int gr = row0 + rr;
      float4 acc = *(const float4*)(sb + ccol);
      for (int k = 0; k < D; ++k) {
        const float hk = sh[rr][k];
        const float4 wv = *(const float4*)(sW + k * 64 + cg * 4);
        acc.x = fmaf(hk, wv.x, acc.x);
        acc.y = fmaf(hk, wv.y, acc.y);
        acc.z = fmaf(hk, wv.z, acc.z);
        acc.w = fmaf(hk, wv.w, acc.w);
      }
      if (gr < N_NODES) {
        *(float4*)(hbuf + (size_t)gr * D + ccol) = acc;
        atomicAdd(&ssum[ccol + 0], acc.x);
        atomicAdd(&ssum[ccol + 1], acc.y);
        atomicAdd(&ssum[ccol + 2], acc.z);
        atomicAdd(&ssum[ccol + 3], acc.w);
        atomicAdd(&ssq[ccol + 0], acc.x * acc.x);
        atomicAdd(&ssq[ccol + 1], acc.y * acc.y);
        atomicAdd(&ssq[ccol + 2], acc.z * acc.z);
        atomicAdd(&ssq[ccol + 3], acc.w * acc.w);
      }
    }
  }
  __syncthreads();
  if (tid < D) {
    atomicAdd(&gsum[tid], ssum[tid]);
    atomicAdd(&gsumsq[tid], ssq[tid]);
  }
}

// ---------------------------------------------------------------------------
// Kernel 3: finalize BN -> per-column affine coefficients A, B.
// hn = h1*A + B with A = gamma*rsqrt(var+eps), B = beta - mean*A.
// ---------------------------------------------------------------------------
__global__ void k_stats(const float* __restrict__ gsum, const float* __restrict__ gsq,
                        const float* __restrict__ gamma, const float* __restrict__ beta,
                        float* __restrict__ coef) {
  const int c = threadIdx.x;
  const float invN = 1.0f / (float)N_NODES;
  const float mean = gsum[c] * invN;
  const float var = gsq[c] * invN - mean * mean;
  const float A = gamma[c] * rsqrtf(var + 1e-5f);
  coef[c] = A;
  coef[D + c] = beta[c] - mean * A;
}

// ---------------------------------------------------------------------------
// Kernel 4: out = relu(h1*A + B) @ W2 + b2. Same tiling as k_gemm1.
// ---------------------------------------------------------------------------
__global__ __launch_bounds__(256) void k_gemm2(
    const float* __restrict__ hbuf, const float* __restrict__ coef,
    const float* __restrict__ W2, const float* __restrict__ b2,
    float* __restrict__ out) {
  __shared__ float sW[64 * D];
  __shared__ float sh[32][D];
  __shared__ float sb[D];
  __shared__ float sA[D];
  __shared__ float sB[D];

  const int tid = threadIdx.x;
  const int row0 = blockIdx.x * 32;

  if (tid < D) { sb[tid] = b2[tid]; sA[tid] = coef[tid]; sB[tid] = coef[D + tid]; }
  __syncthreads();  // sA/sB needed by staging below

  for (int i = tid; i < 1024; i += 256) {
    const int r = i >> 5;
    const int c4 = (i & 31) << 2;
    const int gr = row0 + r;
    float4 hv = make_float4(0.f, 0.f, 0.f, 0.f);
    if (gr < N_NODES) {
      const float4 v = *(const float4*)(hbuf + (size_t)gr * D + c4);
      hv.x = fmaxf(fmaf(v.x, sA[c4 + 0], sB[c4 + 0]), 0.f);
      hv.y = fmaxf(fmaf(v.y, sA[c4 + 1], sB[c4 + 1]), 0.f);
      hv.z = fmaxf(fmaf(v.z, sA[c4 + 2], sB[c4 + 2]), 0.f);
      hv.w = fmaxf(fmaf(v.w, sA[c4 + 3], sB[c4 + 3]), 0.f);
    }
    *(float4*)(&sh[r][c4]) = hv;
  }

  const int cg = tid & 15;
  const int rsub = tid >> 4;

  for (int p = 0; p < 2; ++p) {
    __syncthreads();
    for (int i = tid; i < 2048; i += 256) {
      const int k = i >> 4;
      const int c4 = (i & 15) << 2;
      *(float4*)(sW + k * 64 + c4) = *(const float4*)(W2 + k * D + p * 64 + c4);
    }
    __syncthreads();

    const int ccol = p * 64 + cg * 4;
    for (int t = 0; t < 2; ++t) {
      const int rr = rsub + t * 16;
      const int gr = row0 + rr;
      float4 acc = *(const float4*)(sb + ccol);
      for (int k = 0; k < D; ++k) {
        const float hk = sh[rr][k];
        const float4 wv = *(const float4*)(sW + k * 64 + cg * 4);
        acc.x = fmaf(hk, wv.x, acc.x);
        acc.y = fmaf(hk, wv.y, acc.y);
        acc.z = fmaf(hk, wv.z, acc.z);
        acc.w = fmaf(hk, wv.w, acc.w);
      }
      if (gr < N_NODES) {
        *(float4*)(out + (size_t)gr * D + ccol) = acc;
      }
    }
  }
}

extern "C" void kernel_launch(void* const* d_in, const int* in_sizes, int n_in,
                              void* d_out, int out_size, void* d_ws, size_t ws_size,
                              hipStream_t stream) {
  const float* x    = (const float*)d_in[0];
  const int* ea     = (const int*)d_in[1];
  const int* src    = (const int*)d_in[2];
  const int* dst    = (const int*)d_in[3];
  const float* bemb = (const float*)d_in[4];
  const float* epsp = (const float*)d_in[5];
  const float* W1   = (const float*)d_in[6];
  const float* b1   = (const float*)d_in[7];
  const float* gam  = (const float*)d_in[8];
  const float* bet  = (const float*)d_in[9];
  const float* W2   = (const float*)d_in[10];
  const float* b2   = (const float*)d_in[11];
  float* out = (float*)d_out;

  float* ws     = (float*)d_ws;
  float* hbuf   = ws;                           // N*D: agg, then h1 in-place
  float* gsum   = ws + (size_t)N_NODES * D;     // 128
  float* gsumsq = gsum + D;                     // 128
  float* coef   = gsumsq + D;                   // 256 (A then B)

  // zero agg + stat accumulators each call (ws is poisoned before every launch)
  hipMemsetAsync(ws, 0, ((size_t)N_NODES * D + 2 * D) * sizeof(float), stream);

  k_edge<<<N_EDGES / 8, 256, 0, stream>>>(x, ea, src, dst, bemb, hbuf);
  k_gemm1<<<(N_NODES + 31) / 32, 256, 0, stream>>>(x, epsp, W1, b1, hbuf, gsum, gsumsq);
  k_stats<<<1, D, 0, stream>>>(gsum, gsumsq, gam, bet, coef);
  k_gemm2<<<(N_NODES + 31) / 32, 256, 0, stream>>>(hbuf, coef, W2, b2, out);
}

// Round 2
// 615.339 us; speedup vs baseline: 4.8334x; 4.8334x over previous
//
#include <hip/hip_runtime.h>
#include <hip/hip_bf16.h>

#define NN 50000
#define NE 1600000
#define D 128

__device__ __forceinline__ void fma4(float4& acc, float s, const float4& w) {
  acc.x = fmaf(s, w.x, acc.x);
  acc.y = fmaf(s, w.y, acc.y);
  acc.z = fmaf(s, w.z, acc.z);
  acc.w = fmaf(s, w.w, acc.w);
}

// ---------------------------------------------------------------------------
// K1: histogram of dst. NE == 6250*256 exactly, no guard.
// ---------------------------------------------------------------------------
__global__ __launch_bounds__(256) void k_hist(const int* __restrict__ dst,
                                              int* __restrict__ cnt) {
  const int e = blockIdx.x * 256 + threadIdx.x;
  atomicAdd(&cnt[dst[e]], 1);
}

// ---------------------------------------------------------------------------
// K2: single-block exclusive scan of cnt[NN] -> off[NN+1], plus mutable copy offm.
// ---------------------------------------------------------------------------
__global__ __launch_bounds__(1024) void k_scan(const int* __restrict__ cnt,
                                               int* __restrict__ off,
                                               int* __restrict__ offm) {
  __shared__ int part[1024];
  const int t = threadIdx.x;
  const int CH = 49;  // 49*1024 = 50176 >= NN
  const int base = t * CH;
  int s = 0;
  for (int i = 0; i < CH; ++i) {
    const int idx = base + i;
    if (idx < NN) s += cnt[idx];
  }
  part[t] = s;
  __syncthreads();
  for (int d = 1; d < 1024; d <<= 1) {
    const int v = (t >= d) ? part[t - d] : 0;
    __syncthreads();
    part[t] += v;
    __syncthreads();
  }
  int run = (t == 0) ? 0 : part[t - 1];
  for (int i = 0; i < CH; ++i) {
    const int idx = base + i;
    if (idx < NN) {
      off[idx] = run;
      offm[idx] = run;
      run += cnt[idx];
    }
  }
  if (t == 1023) off[NN] = part[1023];
}

// ---------------------------------------------------------------------------
// K3: scatter packed edge records into CSR order.
// pack = src (16b) | a0<<16 | a1<<20 | a2<<24   (src < 65536, attrs < 5)
// ---------------------------------------------------------------------------
__global__ __launch_bounds__(256) void k_scatter(const int* __restrict__ dst,
                                                 const int* __restrict__ src,
                                                 const int* __restrict__ ea,
                                                 int* __restrict__ offm,
                                                 unsigned* __restrict__ packed) {
  const int e = blockIdx.x * 256 + threadIdx.x;
  const int d = dst[e];
  const int pos = atomicAdd(&offm[d], 1);
  const unsigned pk = (unsigned)src[e] | ((unsigned)ea[e * 3 + 0] << 16) |
                      ((unsigned)ea[e * 3 + 1] << 20) | ((unsigned)ea[e * 3 + 2] << 24);
  packed[pos] = pk;
}

// ---------------------------------------------------------------------------
// K4: per-node aggregation. 32 lanes per node (float4/lane), 8 nodes/block.
// h[n] = (1+eps)*x[n] + sum_{e: dst=n} relu(x[src_e] + emb_e)   (no atomics)
// ---------------------------------------------------------------------------
#define AGG_BODY(p)                                                          \
  {                                                                          \
    const int s = (p) & 0xFFFF;                                              \
    const float4 e0 = *(const float4*)(semb + (((p) >> 16) & 15) * D + col); \
    const float4 e1 = *(const float4*)(semb + (5 + (((p) >> 20) & 15)) * D + col); \
    const float4 e2 = *(const float4*)(semb + (10 + (((p) >> 24) & 15)) * D + col); \
    const float4 xv = *(const float4*)(x + (size_t)s * D + col);             \
    acc.x += fmaxf(xv.x + e0.x + e1.x + e2.x, 0.f);                          \
    acc.y += fmaxf(xv.y + e0.y + e1.y + e2.y, 0.f);                          \
    acc.z += fmaxf(xv.z + e0.z + e1.z + e2.z, 0.f);                          \
    acc.w += fmaxf(xv.w + e0.w + e1.w + e2.w, 0.f);                          \
  }

__global__ __launch_bounds__(256) void k_agg(const float* __restrict__ x,
                                             const float* __restrict__ bemb,
                                             const float* __restrict__ epsp,
                                             const int* __restrict__ off,
                                             const unsigned* __restrict__ packed,
                                             float* __restrict__ hbuf) {
  __shared__ float semb[15 * D];  // 7.5 KB
  for (int i = threadIdx.x; i < 15 * D; i += 256) semb[i] = bemb[i];
  __syncthreads();

  const int lane = threadIdx.x & 31;
  const int grp = threadIdx.x >> 5;
  const int n = blockIdx.x * 8 + grp;  // 6250*8 = 50000 exactly
  const int col = lane << 2;

  const int jb = off[n];
  const int je = off[n + 1];
  float4 acc = make_float4(0.f, 0.f, 0.f, 0.f);

  int j0 = jb;
  for (; j0 + 32 <= je; j0 += 32) {
    const int pk = (int)packed[j0 + lane];  // coalesced; broadcast via shfl
#pragma unroll 8
    for (int t = 0; t < 32; ++t) {
      const unsigned p = (unsigned)__shfl(pk, t, 32);
      AGG_BODY(p)
    }
  }
  if (j0 < je) {
    const int c = je - j0;
    const int pk = (j0 + lane < je) ? (int)packed[j0 + lane] : 0;
    for (int t = 0; t < c; ++t) {
      const unsigned p = (unsigned)__shfl(pk, t, 32);
      AGG_BODY(p)
    }
  }

  const float eps1 = 1.0f + epsp[0];
  const float4 xv = *(const float4*)(x + (size_t)n * D + col);
  acc.x += eps1 * xv.x;
  acc.y += eps1 * xv.y;
  acc.z += eps1 * xv.z;
  acc.w += eps1 * xv.w;
  *(float4*)(hbuf + (size_t)n * D + col) = acc;
}

// ---------------------------------------------------------------------------
// K5: h1 = h @ W1 + b1 (in-place over hbuf) + fused BN column sum/sumsq.
// 64-row tile, 256 threads: 16 col-groups x 16 row-threads, 4 consecutive
// rows/thread, sh padded to 132 (conflict-free), sW staged in 16KB K-halves.
// ---------------------------------------------------------------------------
__global__ __launch_bounds__(256) void k_gemm1(const float* __restrict__ hbuf,
                                               const float* __restrict__ W1,
                                               const float* __restrict__ b1,
                                               float* __restrict__ h1,
                                               float* __restrict__ gsum,
                                               float* __restrict__ gsumsq) {
  __shared__ float sh[64][132];   // 33.8 KB
  __shared__ float sW[64 * 64];   // 16 KB
  __shared__ float ssum[D];
  __shared__ float ssq[D];

  const int tid = threadIdx.x;
  const int row0 = blockIdx.x * 64;
  if (tid < D) { ssum[tid] = 0.f; ssq[tid] = 0.f; }

  for (int i = tid; i < 2048; i += 256) {
    const int r = i >> 5;
    const int c4 = (i & 31) << 2;
    const int gr = row0 + r;
    float4 v = make_float4(0.f, 0.f, 0.f, 0.f);
    if (gr < NN) v = *(const float4*)(hbuf + (size_t)gr * D + c4);
    *(float4*)(&sh[r][c4]) = v;
  }

  const int cg = tid & 15;
  const int rt = tid >> 4;
  const int r0 = rt * 4;  // 4 consecutive rows

  for (int p = 0; p < 2; ++p) {
    const int ccol = p * 64 + cg * 4;
    float4 acc0, acc1, acc2, acc3;
    for (int kh = 0; kh < 2; ++kh) {
      __syncthreads();  // protect sW rewrite (and initial sh staging)
      for (int i = tid; i < 1024; i += 256) {
        const int k = i >> 4;
        const int c4 = (i & 15) << 2;
        *(float4*)(sW + k * 64 + c4) =
            *(const float4*)(W1 + (size_t)(kh * 64 + k) * D + p * 64 + c4);
      }
      __syncthreads();
      if (kh == 0) {
        const float4 bias = *(const float4*)(b1 + ccol);
        acc0 = bias; acc1 = bias; acc2 = bias; acc3 = bias;
      }
      const int kb = kh * 64;
      for (int k = 0; k < 64; k += 4) {
        const float4 w0 = *(const float4*)(sW + (k + 0) * 64 + cg * 4);
        const float4 w1 = *(const float4*)(sW + (k + 1) * 64 + cg * 4);
        const float4 w2 = *(const float4*)(sW + (k + 2) * 64 + cg * 4);
        const float4 w3 = *(const float4*)(sW + (k + 3) * 64 + cg * 4);
        const float4 a0 = *(const float4*)(&sh[r0 + 0][kb + k]);
        const float4 a1 = *(const float4*)(&sh[r0 + 1][kb + k]);
        const float4 a2 = *(const float4*)(&sh[r0 + 2][kb + k]);
        const float4 a3 = *(const float4*)(&sh[r0 + 3][kb + k]);
        fma4(acc0, a0.x, w0); fma4(acc0, a0.y, w1); fma4(acc0, a0.z, w2); fma4(acc0, a0.w, w3);
        fma4(acc1, a1.x, w0); fma4(acc1, a1.y, w1); fma4(acc1, a1.z, w2); fma4(acc1, a1.w, w3);
        fma4(acc2, a2.x, w0); fma4(acc2, a2.y, w1); fma4(acc2, a2.z, w2); fma4(acc2, a2.w, w3);
        fma4(acc3, a3.x, w0); fma4(acc3, a3.y, w1); fma4(acc3, a3.z, w2); fma4(acc3, a3.w, w3);
      }
    }
    // store + local BN stats for this pass's 4 columns
    float4 ls = make_float4(0.f, 0.f, 0.f, 0.f);
    float4 lq = make_float4(0.f, 0.f, 0.f, 0.f);
    const float4* accs[4] = {&acc0, &acc1, &acc2, &acc3};
    for (int q = 0; q < 4; ++q) {
      const int gr = row0 + r0 + q;
      if (gr < NN) {
        const float4 a = *accs[q];
        *(float4*)(h1 + (size_t)gr * D + ccol) = a;
        ls.x += a.x; ls.y += a.y; ls.z += a.z; ls.w += a.w;
        lq.x += a.x * a.x; lq.y += a.y * a.y; lq.z += a.z * a.z; lq.w += a.w * a.w;
      }
    }
    atomicAdd(&ssum[ccol + 0], ls.x);
    atomicAdd(&ssum[ccol + 1], ls.y);
    atomicAdd(&ssum[ccol + 2], ls.z);
    atomicAdd(&ssum[ccol + 3], ls.w);
    atomicAdd(&ssq[ccol + 0], lq.x);
    atomicAdd(&ssq[ccol + 1], lq.y);
    atomicAdd(&ssq[ccol + 2], lq.z);
    atomicAdd(&ssq[ccol + 3], lq.w);
  }
  __syncthreads();
  if (tid < D) {
    atomicAdd(&gsum[tid], ssum[tid]);
    atomicAdd(&gsumsq[tid], ssq[tid]);
  }
}

// ---------------------------------------------------------------------------
// K6: BN finalize -> per-column affine A, B.
// ---------------------------------------------------------------------------
__global__ void k_stats(const float* __restrict__ gsum, const float* __restrict__ gsq,
                        const float* __restrict__ gamma, const float* __restrict__ beta,
                        float* __restrict__ coef) {
  const int c = threadIdx.x;
  const float invN = 1.0f / (float)NN;
  const float mean = gsum[c] * invN;
  const float var = gsq[c] * invN - mean * mean;
  const float A = gamma[c] * rsqrtf(var + 1e-5f);
  coef[c] = A;
  coef[D + c] = beta[c] - mean * A;
}

// ---------------------------------------------------------------------------
// K7: out = relu(h1*A + B) @ W2 + b2. Same tiling as K5; affine+relu fused
// into the LDS staging.
// ---------------------------------------------------------------------------
__global__ __launch_bounds__(256) void k_gemm2(const float* __restrict__ hbuf,
                                               const float* __restrict__ coef,
                                               const float* __restrict__ W2,
                                               const float* __restrict__ b2,
                                               float* __restrict__ out) {
  __shared__ float sh[64][132];
  __shared__ float sW[64 * 64];

  const int tid = threadIdx.x;
  const int row0 = blockIdx.x * 64;

  for (int i = tid; i < 2048; i += 256) {
    const int r = i >> 5;
    const int c4 = (i & 31) << 2;
    const int gr = row0 + r;
    float4 v = make_float4(0.f, 0.f, 0.f, 0.f);
    if (gr < NN) {
      const float4 h = *(const float4*)(hbuf + (size_t)gr * D + c4);
      const float4 A = *(const float4*)(coef + c4);
      const float4 B = *(const float4*)(coef + D + c4);
      v.x = fmaxf(fmaf(h.x, A.x, B.x), 0.f);
      v.y = fmaxf(fmaf(h.y, A.y, B.y), 0.f);
      v.z = fmaxf(fmaf(h.z, A.z, B.z), 0.f);
      v.w = fmaxf(fmaf(h.w, A.w, B.w), 0.f);
    }
    *(float4*)(&sh[r][c4]) = v;
  }

  const int cg = tid & 15;
  const int rt = tid >> 4;
  const int r0 = rt * 4;

  for (int p = 0; p < 2; ++p) {
    const int ccol = p * 64 + cg * 4;
    float4 acc0, acc1, acc2, acc3;
    for (int kh = 0; kh < 2; ++kh) {
      __syncthreads();
      for (int i = tid; i < 1024; i += 256) {
        const int k = i >> 4;
        const int c4 = (i & 15) << 2;
        *(float4*)(sW + k * 64 + c4) =
            *(const float4*)(W2 + (size_t)(kh * 64 + k) * D + p * 64 + c4);
      }
      __syncthreads();
      if (kh == 0) {
        const float4 bias = *(const float4*)(b2 + ccol);
        acc0 = bias; acc1 = bias; acc2 = bias; acc3 = bias;
      }
      const int kb = kh * 64;
      for (int k = 0; k < 64; k += 4) {
        const float4 w0 = *(const float4*)(sW + (k + 0) * 64 + cg * 4);
        const float4 w1 = *(const float4*)(sW + (k + 1) * 64 + cg * 4);
        const float4 w2 = *(const float4*)(sW + (k + 2) * 64 + cg * 4);
        const float4 w3 = *(const float4*)(sW + (k + 3) * 64 + cg * 4);
        const float4 a0 = *(const float4*)(&sh[r0 + 0][kb + k]);
        const float4 a1 = *(const float4*)(&sh[r0 + 1][kb + k]);
        const float4 a2 = *(const float4*)(&sh[r0 + 2][kb + k]);
        const float4 a3 = *(const float4*)(&sh[r0 + 3][kb + k]);
        fma4(acc0, a0.x, w0); fma4(acc0, a0.y, w1); fma4(acc0, a0.z, w2); fma4(acc0, a0.w, w3);
        fma4(acc1, a1.x, w0); fma4(acc1, a1.y, w1); fma4(acc1, a1.z, w2); fma4(acc1, a1.w, w3);
        fma4(acc2, a2.x, w0); fma4(acc2, a2.y, w1); fma4(acc2, a2.z, w2); fma4(acc2, a2.w, w3);
        fma4(acc3, a3.x, w0); fma4(acc3, a3.y, w1); fma4(acc3, a3.z, w2); fma4(acc3, a3.w, w3);
      }
    }
    for (int q = 0; q < 4; ++q) {
      const int gr = row0 + r0 + q;
      if (gr < NN) {
        const float4* accs[4] = {&acc0, &acc1, &acc2, &acc3};
        *(float4*)(out + (size_t)gr * D + ccol) = *accs[q];
      }
    }
  }
}

extern "C" void kernel_launch(void* const* d_in, const int* in_sizes, int n_in,
                              void* d_out, int out_size, void* d_ws, size_t ws_size,
                              hipStream_t stream) {
  const float* x    = (const float*)d_in[0];
  const int* ea     = (const int*)d_in[1];
  const int* src    = (const int*)d_in[2];
  const int* dst    = (const int*)d_in[3];
  const float* bemb = (const float*)d_in[4];
  const float* epsp = (const float*)d_in[5];
  const float* W1   = (const float*)d_in[6];
  const float* b1   = (const float*)d_in[7];
  const float* gam  = (const float*)d_in[8];
  const float* bet  = (const float*)d_in[9];
  const float* W2   = (const float*)d_in[10];
  const float* b2   = (const float*)d_in[11];
  float* out = (float*)d_out;

  // workspace layout (floats/ints are both 4 B)
  float* ws       = (float*)d_ws;
  float* hbuf     = ws;                                  // NN*D
  int* cnt        = (int*)(ws + (size_t)NN * D);         // NN   (zeroed)
  float* gsum     = ws + (size_t)NN * D + NN;            // 128  (zeroed)
  float* gsumsq   = gsum + D;                            // 128  (zeroed)
  float* coef     = gsumsq + D;                          // 256
  int* off        = (int*)(coef + 2 * D);                // NN+1
  int* offm       = off + NN + 1;                        // NN
  unsigned* packed = (unsigned*)(offm + NN);             // NE

  hipMemsetAsync(cnt, 0, (size_t)(NN + 2 * D) * sizeof(int), stream);

  k_hist<<<NE / 256, 256, 0, stream>>>(dst, cnt);
  k_scan<<<1, 1024, 0, stream>>>(cnt, off, offm);
  k_scatter<<<NE / 256, 256, 0, stream>>>(dst, src, ea, offm, packed);
  k_agg<<<NN / 8, 256, 0, stream>>>(x, bemb, epsp, off, packed, hbuf);
  k_gemm1<<<(NN + 63) / 64, 256, 0, stream>>>(hbuf, W1, b1, hbuf, gsum, gsumsq);
  k_stats<<<1, D, 0, stream>>>(gsum, gsumsq, gam, bet, coef);
  k_gemm2<<<(NN + 63) / 64, 256, 0, stream>>>(hbuf, coef, W2, b2, out);
}

// Round 3
// 415.758 us; speedup vs baseline: 7.1536x; 1.4800x over previous
//
#include <hip/hip_runtime.h>
#include <hip/hip_bf16.h>

#define NN 50000
#define NE 1600000
#define D 128
#define MAXDEG 80   // Poisson(32): P(deg>80)*NN ~ 2.5e-8; guarded anyway

__device__ __forceinline__ void fma4(float4& acc, float s, const float4& w) {
  acc.x = fmaf(s, w.x, acc.x);
  acc.y = fmaf(s, w.y, acc.y);
  acc.z = fmaf(s, w.z, acc.z);
  acc.w = fmaf(s, w.w, acc.w);
}

// ---------------------------------------------------------------------------
// K0: build combined bond-embedding table: ctab[combo][k] = e0[a0]+e1[a1]+e2[a2]
// combo = (a0*5 + a1)*5 + a2, 125 combos x 128 = 64 KB, L2-hot thereafter.
// ---------------------------------------------------------------------------
__global__ __launch_bounds__(256) void k_prep(const float* __restrict__ bemb,
                                              float* __restrict__ ctab) {
  const int idx = blockIdx.x * 256 + threadIdx.x;
  if (idx >= 125 * D) return;
  const int c = idx >> 7;
  const int k = idx & 127;
  const int a0 = c / 25;
  const int a1 = (c % 25) / 5;
  const int a2 = c % 5;
  ctab[idx] = bemb[a0 * D + k] + bemb[(5 + a1) * D + k] + bemb[(10 + a2) * D + k];
}

// ---------------------------------------------------------------------------
// K1: fused slot-scatter (replaces hist+scan+scatter).
// pos = atomicAdd(cnt[dst]); packed[dst*MAXDEG+pos] = src | combo<<16
// ---------------------------------------------------------------------------
__global__ __launch_bounds__(256) void k_scatter(const int* __restrict__ dst,
                                                 const int* __restrict__ src,
                                                 const int* __restrict__ ea,
                                                 int* __restrict__ cnt,
                                                 unsigned* __restrict__ packed) {
  const int e = blockIdx.x * 256 + threadIdx.x;  // NE % 256 == 0
  const int d = dst[e];
  const int combo = (ea[e * 3 + 0] * 5 + ea[e * 3 + 1]) * 5 + ea[e * 3 + 2];
  const int pos = atomicAdd(&cnt[d], 1);
  if (pos < MAXDEG)
    packed[(size_t)d * MAXDEG + pos] = (unsigned)src[e] | ((unsigned)combo << 16);
}

// ---------------------------------------------------------------------------
// K2: per-node aggregation, no LDS, no atomics.
// h[n] = (1+eps)*x[n] + sum relu(x[src] + ctab[combo]) ; 32 lanes/node.
// ---------------------------------------------------------------------------
#define AGG_BODY(p)                                                      \
  {                                                                      \
    const int s = (p) & 0xFFFF;                                          \
    const int cb = ((p) >> 16) & 0x7F;                                   \
    const float4 ev = *(const float4*)(ctab + cb * D + col);             \
    const float4 xv = *(const float4*)(x + (size_t)s * D + col);         \
    acc.x += fmaxf(xv.x + ev.x, 0.f);                                    \
    acc.y += fmaxf(xv.y + ev.y, 0.f);                                    \
    acc.z += fmaxf(xv.z + ev.z, 0.f);                                    \
    acc.w += fmaxf(xv.w + ev.w, 0.f);                                    \
  }

__global__ __launch_bounds__(256) void k_agg(const float* __restrict__ x,
                                             const float* __restrict__ ctab,
                                             const float* __restrict__ epsp,
                                             const int* __restrict__ cnt,
                                             const unsigned* __restrict__ packed,
                                             float* __restrict__ hbuf) {
  const int lane = threadIdx.x & 31;
  const int n = blockIdx.x * 8 + (threadIdx.x >> 5);  // 6250*8 = NN exactly
  const int col = lane << 2;

  const unsigned* seg = packed + (size_t)n * MAXDEG;
  const int deg = min(cnt[n], MAXDEG);
  float4 acc = make_float4(0.f, 0.f, 0.f, 0.f);

  int j0 = 0;
  for (; j0 + 32 <= deg; j0 += 32) {
    const int pk = (int)seg[j0 + lane];  // coalesced; broadcast via shfl
#pragma unroll 8
    for (int t = 0; t < 32; ++t) {
      const unsigned p = (unsigned)__shfl(pk, t, 32);
      AGG_BODY(p)
    }
  }
  if (j0 < deg) {
    const int c = deg - j0;
    const int pk = (j0 + lane < deg) ? (int)seg[j0 + lane] : 0;
    for (int t = 0; t < c; ++t) {
      const unsigned p = (unsigned)__shfl(pk, t, 32);
      AGG_BODY(p)
    }
  }

  const float eps1 = 1.0f + epsp[0];
  const float4 xv = *(const float4*)(x + (size_t)n * D + col);
  acc.x += eps1 * xv.x;
  acc.y += eps1 * xv.y;
  acc.z += eps1 * xv.z;
  acc.w += eps1 * xv.w;
  *(float4*)(hbuf + (size_t)n * D + col) = acc;
}

// ---------------------------------------------------------------------------
// K3: h1 = h @ W1 + b1 (in-place over hbuf) + fused BN column sum/sumsq.
// (unchanged from R2 — control)
// ---------------------------------------------------------------------------
__global__ __launch_bounds__(256) void k_gemm1(const float* __restrict__ hbuf,
                                               const float* __restrict__ W1,
                                               const float* __restrict__ b1,
                                               float* __restrict__ h1,
                                               float* __restrict__ gsum,
                                               float* __restrict__ gsumsq) {
  __shared__ float sh[64][132];
  __shared__ float sW[64 * 64];
  __shared__ float ssum[D];
  __shared__ float ssq[D];

  const int tid = threadIdx.x;
  const int row0 = blockIdx.x * 64;
  if (tid < D) { ssum[tid] = 0.f; ssq[tid] = 0.f; }

  for (int i = tid; i < 2048; i += 256) {
    const int r = i >> 5;
    const int c4 = (i & 31) << 2;
    const int gr = row0 + r;
    float4 v = make_float4(0.f, 0.f, 0.f, 0.f);
    if (gr < NN) v = *(const float4*)(hbuf + (size_t)gr * D + c4);
    *(float4*)(&sh[r][c4]) = v;
  }

  const int cg = tid & 15;
  const int rt = tid >> 4;
  const int r0 = rt * 4;

  for (int p = 0; p < 2; ++p) {
    const int ccol = p * 64 + cg * 4;
    float4 acc0, acc1, acc2, acc3;
    for (int kh = 0; kh < 2; ++kh) {
      __syncthreads();
      for (int i = tid; i < 1024; i += 256) {
        const int k = i >> 4;
        const int c4 = (i & 15) << 2;
        *(float4*)(sW + k * 64 + c4) =
            *(const float4*)(W1 + (size_t)(kh * 64 + k) * D + p * 64 + c4);
      }
      __syncthreads();
      if (kh == 0) {
        const float4 bias = *(const float4*)(b1 + ccol);
        acc0 = bias; acc1 = bias; acc2 = bias; acc3 = bias;
      }
      const int kb = kh * 64;
      for (int k = 0; k < 64; k += 4) {
        const float4 w0 = *(const float4*)(sW + (k + 0) * 64 + cg * 4);
        const float4 w1 = *(const float4*)(sW + (k + 1) * 64 + cg * 4);
        const float4 w2 = *(const float4*)(sW + (k + 2) * 64 + cg * 4);
        const float4 w3 = *(const float4*)(sW + (k + 3) * 64 + cg * 4);
        const float4 a0 = *(const float4*)(&sh[r0 + 0][kb + k]);
        const float4 a1 = *(const float4*)(&sh[r0 + 1][kb + k]);
        const float4 a2 = *(const float4*)(&sh[r0 + 2][kb + k]);
        const float4 a3 = *(const float4*)(&sh[r0 + 3][kb + k]);
        fma4(acc0, a0.x, w0); fma4(acc0, a0.y, w1); fma4(acc0, a0.z, w2); fma4(acc0, a0.w, w3);
        fma4(acc1, a1.x, w0); fma4(acc1, a1.y, w1); fma4(acc1, a1.z, w2); fma4(acc1, a1.w, w3);
        fma4(acc2, a2.x, w0); fma4(acc2, a2.y, w1); fma4(acc2, a2.z, w2); fma4(acc2, a2.w, w3);
        fma4(acc3, a3.x, w0); fma4(acc3, a3.y, w1); fma4(acc3, a3.z, w2); fma4(acc3, a3.w, w3);
      }
    }
    float4 ls = make_float4(0.f, 0.f, 0.f, 0.f);
    float4 lq = make_float4(0.f, 0.f, 0.f, 0.f);
    const float4* accs[4] = {&acc0, &acc1, &acc2, &acc3};
    for (int q = 0; q < 4; ++q) {
      const int gr = row0 + r0 + q;
      if (gr < NN) {
        const float4 a = *accs[q];
        *(float4*)(h1 + (size_t)gr * D + ccol) = a;
        ls.x += a.x; ls.y += a.y; ls.z += a.z; ls.w += a.w;
        lq.x += a.x * a.x; lq.y += a.y * a.y; lq.z += a.z * a.z; lq.w += a.w * a.w;
      }
    }
    atomicAdd(&ssum[ccol + 0], ls.x);
    atomicAdd(&ssum[ccol + 1], ls.y);
    atomicAdd(&ssum[ccol + 2], ls.z);
    atomicAdd(&ssum[ccol + 3], ls.w);
    atomicAdd(&ssq[ccol + 0], lq.x);
    atomicAdd(&ssq[ccol + 1], lq.y);
    atomicAdd(&ssq[ccol + 2], lq.z);
    atomicAdd(&ssq[ccol + 3], lq.w);
  }
  __syncthreads();
  if (tid < D) {
    atomicAdd(&gsum[tid], ssum[tid]);
    atomicAdd(&gsumsq[tid], ssq[tid]);
  }
}

// ---------------------------------------------------------------------------
// K4: BN finalize -> per-column affine A, B.
// ---------------------------------------------------------------------------
__global__ void k_stats(const float* __restrict__ gsum, const float* __restrict__ gsq,
                        const float* __restrict__ gamma, const float* __restrict__ beta,
                        float* __restrict__ coef) {
  const int c = threadIdx.x;
  const float invN = 1.0f / (float)NN;
  const float mean = gsum[c] * invN;
  const float var = gsq[c] * invN - mean * mean;
  const float A = gamma[c] * rsqrtf(var + 1e-5f);
  coef[c] = A;
  coef[D + c] = beta[c] - mean * A;
}

// ---------------------------------------------------------------------------
// K5: out = relu(h1*A + B) @ W2 + b2. (unchanged from R2 — control)
// ---------------------------------------------------------------------------
__global__ __launch_bounds__(256) void k_gemm2(const float* __restrict__ hbuf,
                                               const float* __restrict__ coef,
                                               const float* __restrict__ W2,
                                               const float* __restrict__ b2,
                                               float* __restrict__ out) {
  __shared__ float sh[64][132];
  __shared__ float sW[64 * 64];

  const int tid = threadIdx.x;
  const int row0 = blockIdx.x * 64;

  for (int i = tid; i < 2048; i += 256) {
    const int r = i >> 5;
    const int c4 = (i & 31) << 2;
    const int gr = row0 + r;
    float4 v = make_float4(0.f, 0.f, 0.f, 0.f);
    if (gr < NN) {
      const float4 h = *(const float4*)(hbuf + (size_t)gr * D + c4);
      const float4 A = *(const float4*)(coef + c4);
      const float4 B = *(const float4*)(coef + D + c4);
      v.x = fmaxf(fmaf(h.x, A.x, B.x), 0.f);
      v.y = fmaxf(fmaf(h.y, A.y, B.y), 0.f);
      v.z = fmaxf(fmaf(h.z, A.z, B.z), 0.f);
      v.w = fmaxf(fmaf(h.w, A.w, B.w), 0.f);
    }
    *(float4*)(&sh[r][c4]) = v;
  }

  const int cg = tid & 15;
  const int rt = tid >> 4;
  const int r0 = rt * 4;

  for (int p = 0; p < 2; ++p) {
    const int ccol = p * 64 + cg * 4;
    float4 acc0, acc1, acc2, acc3;
    for (int kh = 0; kh < 2; ++kh) {
      __syncthreads();
      for (int i = tid; i < 1024; i += 256) {
        const int k = i >> 4;
        const int c4 = (i & 15) << 2;
        *(float4*)(sW + k * 64 + c4) =
            *(const float4*)(W2 + (size_t)(kh * 64 + k) * D + p * 64 + c4);
      }
      __syncthreads();
      if (kh == 0) {
        const float4 bias = *(const float4*)(b2 + ccol);
        acc0 = bias; acc1 = bias; acc2 = bias; acc3 = bias;
      }
      const int kb = kh * 64;
      for (int k = 0; k < 64; k += 4) {
        const float4 w0 = *(const float4*)(sW + (k + 0) * 64 + cg * 4);
        const float4 w1 = *(const float4*)(sW + (k + 1) * 64 + cg * 4);
        const float4 w2 = *(const float4*)(sW + (k + 2) * 64 + cg * 4);
        const float4 w3 = *(const float4*)(sW + (k + 3) * 64 + cg * 4);
        const float4 a0 = *(const float4*)(&sh[r0 + 0][kb + k]);
        const float4 a1 = *(const float4*)(&sh[r0 + 1][kb + k]);
        const float4 a2 = *(const float4*)(&sh[r0 + 2][kb + k]);
        const float4 a3 = *(const float4*)(&sh[r0 + 3][kb + k]);
        fma4(acc0, a0.x, w0); fma4(acc0, a0.y, w1); fma4(acc0, a0.z, w2); fma4(acc0, a0.w, w3);
        fma4(acc1, a1.x, w0); fma4(acc1, a1.y, w1); fma4(acc1, a1.z, w2); fma4(acc1, a1.w, w3);
        fma4(acc2, a2.x, w0); fma4(acc2, a2.y, w1); fma4(acc2, a2.z, w2); fma4(acc2, a2.w, w3);
        fma4(acc3, a3.x, w0); fma4(acc3, a3.y, w1); fma4(acc3, a3.z, w2); fma4(acc3, a3.w, w3);
      }
    }
    for (int q = 0; q < 4; ++q) {
      const int gr = row0 + r0 + q;
      if (gr < NN) {
        const float4* accs[4] = {&acc0, &acc1, &acc2, &acc3};
        *(float4*)(out + (size_t)gr * D + ccol) = *accs[q];
      }
    }
  }
}

extern "C" void kernel_launch(void* const* d_in, const int* in_sizes, int n_in,
                              void* d_out, int out_size, void* d_ws, size_t ws_size,
                              hipStream_t stream) {
  const float* x    = (const float*)d_in[0];
  const int* ea     = (const int*)d_in[1];
  const int* src    = (const int*)d_in[2];
  const int* dst    = (const int*)d_in[3];
  const float* bemb = (const float*)d_in[4];
  const float* epsp = (const float*)d_in[5];
  const float* W1   = (const float*)d_in[6];
  const float* b1   = (const float*)d_in[7];
  const float* gam  = (const float*)d_in[8];
  const float* bet  = (const float*)d_in[9];
  const float* W2   = (const float*)d_in[10];
  const float* b2   = (const float*)d_in[11];
  float* out = (float*)d_out;

  // workspace layout (all 4 B elements)
  float* ws        = (float*)d_ws;
  float* hbuf      = ws;                                 // NN*D
  int* cnt         = (int*)(ws + (size_t)NN * D);        // NN    (zeroed)
  float* gsum      = ws + (size_t)NN * D + NN;           // 128   (zeroed)
  float* gsumsq    = gsum + D;                           // 128   (zeroed)
  float* coef      = gsumsq + D;                         // 256
  float* ctab      = coef + 2 * D;                       // 125*128
  unsigned* packed = (unsigned*)(ctab + 125 * D);        // NN*MAXDEG (16 MB)

  hipMemsetAsync(cnt, 0, (size_t)(NN + 2 * D) * sizeof(int), stream);

  k_prep<<<(125 * D + 255) / 256, 256, 0, stream>>>(bemb, ctab);
  k_scatter<<<NE / 256, 256, 0, stream>>>(dst, src, ea, cnt, packed);
  k_agg<<<NN / 8, 256, 0, stream>>>(x, ctab, epsp, cnt, packed, hbuf);
  k_gemm1<<<(NN + 63) / 64, 256, 0, stream>>>(hbuf, W1, b1, hbuf, gsum, gsumsq);
  k_stats<<<1, D, 0, stream>>>(gsum, gsumsq, gam, bet, coef);
  k_gemm2<<<(NN + 63) / 64, 256, 0, stream>>>(hbuf, coef, W2, b2, out);
}

// Round 4
// 402.979 us; speedup vs baseline: 7.3805x; 1.0317x over previous
//
#include <hip/hip_runtime.h>
#include <hip/hip_bf16.h>

#define NN 50000
#define NE 1600000
#define D 128
#define MAXDEG 80   // Poisson(32): P(deg>80)*NN ~ 2.5e-8; guarded anyway

__device__ __forceinline__ void fma4(float4& acc, float s, const float4& w) {
  acc.x = fmaf(s, w.x, acc.x);
  acc.y = fmaf(s, w.y, acc.y);
  acc.z = fmaf(s, w.z, acc.z);
  acc.w = fmaf(s, w.w, acc.w);
}

// ---------------------------------------------------------------------------
// K1: fused slot-scatter + ctab build. 4 edges/thread, int4 loads.
// pos = atomicAdd(cnt[dst]); packed[dst*MAXDEG+pos] = src | combo<<16
// ctab[combo][k] = e0[a0]+e1[a1]+e2[a2]  (125*128 fp32, L2-hot for k_agg)
// ---------------------------------------------------------------------------
__global__ __launch_bounds__(256) void k_scatter(const int* __restrict__ dst,
                                                 const int* __restrict__ src,
                                                 const int* __restrict__ ea,
                                                 const float* __restrict__ bemb,
                                                 int* __restrict__ cnt,
                                                 unsigned* __restrict__ packed,
                                                 float* __restrict__ ctab) {
  const int gid = blockIdx.x * 256 + threadIdx.x;

  // fold ctab build into the first 63 blocks (16000 threads)
  if (gid < 125 * D) {
    const int c = gid >> 7;
    const int k = gid & 127;
    ctab[gid] = bemb[(c / 25) * D + k] + bemb[(5 + (c % 25) / 5) * D + k] +
                bemb[(10 + c % 5) * D + k];
  }

  const int e0 = gid * 4;
  if (e0 >= NE) return;

  const int4 d4 = *(const int4*)(dst + e0);
  const int4 s4 = *(const int4*)(src + e0);
  const int4 a0 = *(const int4*)(ea + 3 * e0);
  const int4 a1 = *(const int4*)(ea + 3 * e0 + 4);
  const int4 a2 = *(const int4*)(ea + 3 * e0 + 8);

  const int cb0 = (a0.x * 5 + a0.y) * 5 + a0.z;
  const int cb1 = (a0.w * 5 + a1.x) * 5 + a1.y;
  const int cb2 = (a1.z * 5 + a1.w) * 5 + a2.x;
  const int cb3 = (a2.y * 5 + a2.z) * 5 + a2.w;

  int p;
  p = atomicAdd(&cnt[d4.x], 1);
  if (p < MAXDEG) packed[(size_t)d4.x * MAXDEG + p] = (unsigned)s4.x | ((unsigned)cb0 << 16);
  p = atomicAdd(&cnt[d4.y], 1);
  if (p < MAXDEG) packed[(size_t)d4.y * MAXDEG + p] = (unsigned)s4.y | ((unsigned)cb1 << 16);
  p = atomicAdd(&cnt[d4.z], 1);
  if (p < MAXDEG) packed[(size_t)d4.z * MAXDEG + p] = (unsigned)s4.z | ((unsigned)cb2 << 16);
  p = atomicAdd(&cnt[d4.w], 1);
  if (p < MAXDEG) packed[(size_t)d4.w * MAXDEG + p] = (unsigned)s4.w | ((unsigned)cb3 << 16);
}

// ---------------------------------------------------------------------------
// K2: per-node aggregation. 32 lanes/node, batch-of-4 edges for ILP
// (8 independent float4 loads in flight before any use).
// ---------------------------------------------------------------------------
#define EDGE1(p)                                                         \
  {                                                                      \
    const float4 ev = *(const float4*)(ctab + (((p) >> 16) & 0x7F) * D + col); \
    const float4 xv = *(const float4*)(x + (size_t)((p) & 0xFFFF) * D + col); \
    acc.x += fmaxf(xv.x + ev.x, 0.f);                                    \
    acc.y += fmaxf(xv.y + ev.y, 0.f);                                    \
    acc.z += fmaxf(xv.z + ev.z, 0.f);                                    \
    acc.w += fmaxf(xv.w + ev.w, 0.f);                                    \
  }

__global__ __launch_bounds__(256) void k_agg(const float* __restrict__ x,
                                             const float* __restrict__ ctab,
                                             const float* __restrict__ epsp,
                                             const int* __restrict__ cnt,
                                             const unsigned* __restrict__ packed,
                                             float* __restrict__ hbuf) {
  const int lane = threadIdx.x & 31;
  const int n = blockIdx.x * 8 + (threadIdx.x >> 5);  // 6250*8 = NN exactly
  const int col = lane << 2;

  const unsigned* seg = packed + (size_t)n * MAXDEG;
  const int deg = min(cnt[n], MAXDEG);
  float4 acc = make_float4(0.f, 0.f, 0.f, 0.f);

  for (int jb = 0; jb < deg; jb += 32) {
    const int rem = min(32, deg - jb);
    const int pk = (jb + lane < deg) ? (int)seg[jb + lane] : 0;
    int t = 0;
    for (; t + 4 <= rem; t += 4) {
      const unsigned p0 = (unsigned)__shfl(pk, t + 0, 32);
      const unsigned p1 = (unsigned)__shfl(pk, t + 1, 32);
      const unsigned p2 = (unsigned)__shfl(pk, t + 2, 32);
      const unsigned p3 = (unsigned)__shfl(pk, t + 3, 32);
      // 8 independent loads issued back-to-back
      const float4 x0 = *(const float4*)(x + (size_t)(p0 & 0xFFFF) * D + col);
      const float4 e0 = *(const float4*)(ctab + ((p0 >> 16) & 0x7F) * D + col);
      const float4 x1 = *(const float4*)(x + (size_t)(p1 & 0xFFFF) * D + col);
      const float4 e1 = *(const float4*)(ctab + ((p1 >> 16) & 0x7F) * D + col);
      const float4 x2 = *(const float4*)(x + (size_t)(p2 & 0xFFFF) * D + col);
      const float4 e2 = *(const float4*)(ctab + ((p2 >> 16) & 0x7F) * D + col);
      const float4 x3 = *(const float4*)(x + (size_t)(p3 & 0xFFFF) * D + col);
      const float4 e3 = *(const float4*)(ctab + ((p3 >> 16) & 0x7F) * D + col);
      acc.x += fmaxf(x0.x + e0.x, 0.f) + fmaxf(x1.x + e1.x, 0.f) +
               fmaxf(x2.x + e2.x, 0.f) + fmaxf(x3.x + e3.x, 0.f);
      acc.y += fmaxf(x0.y + e0.y, 0.f) + fmaxf(x1.y + e1.y, 0.f) +
               fmaxf(x2.y + e2.y, 0.f) + fmaxf(x3.y + e3.y, 0.f);
      acc.z += fmaxf(x0.z + e0.z, 0.f) + fmaxf(x1.z + e1.z, 0.f) +
               fmaxf(x2.z + e2.z, 0.f) + fmaxf(x3.z + e3.z, 0.f);
      acc.w += fmaxf(x0.w + e0.w, 0.f) + fmaxf(x1.w + e1.w, 0.f) +
               fmaxf(x2.w + e2.w, 0.f) + fmaxf(x3.w + e3.w, 0.f);
    }
    for (; t < rem; ++t) {
      const unsigned p = (unsigned)__shfl(pk, t, 32);
      EDGE1(p)
    }
  }

  const float eps1 = 1.0f + epsp[0];
  const float4 xv = *(const float4*)(x + (size_t)n * D + col);
  acc.x += eps1 * xv.x;
  acc.y += eps1 * xv.y;
  acc.z += eps1 * xv.z;
  acc.w += eps1 * xv.w;
  *(float4*)(hbuf + (size_t)n * D + col) = acc;
}

// ---------------------------------------------------------------------------
// K3: h1 = h @ W1 + b1 (in-place over hbuf) + fused BN column sum/sumsq.
// ---------------------------------------------------------------------------
__global__ __launch_bounds__(256) void k_gemm1(const float* __restrict__ hbuf,
                                               const float* __restrict__ W1,
                                               const float* __restrict__ b1,
                                               float* __restrict__ h1,
                                               float* __restrict__ gsum,
                                               float* __restrict__ gsumsq) {
  __shared__ float sh[64][132];
  __shared__ float sW[64 * 64];
  __shared__ float ssum[D];
  __shared__ float ssq[D];

  const int tid = threadIdx.x;
  const int row0 = blockIdx.x * 64;
  if (tid < D) { ssum[tid] = 0.f; ssq[tid] = 0.f; }

  for (int i = tid; i < 2048; i += 256) {
    const int r = i >> 5;
    const int c4 = (i & 31) << 2;
    const int gr = row0 + r;
    float4 v = make_float4(0.f, 0.f, 0.f, 0.f);
    if (gr < NN) v = *(const float4*)(hbuf + (size_t)gr * D + c4);
    *(float4*)(&sh[r][c4]) = v;
  }

  const int cg = tid & 15;
  const int rt = tid >> 4;
  const int r0 = rt * 4;

  for (int p = 0; p < 2; ++p) {
    const int ccol = p * 64 + cg * 4;
    float4 acc0, acc1, acc2, acc3;
    for (int kh = 0; kh < 2; ++kh) {
      __syncthreads();
      for (int i = tid; i < 1024; i += 256) {
        const int k = i >> 4;
        const int c4 = (i & 15) << 2;
        *(float4*)(sW + k * 64 + c4) =
            *(const float4*)(W1 + (size_t)(kh * 64 + k) * D + p * 64 + c4);
      }
      __syncthreads();
      if (kh == 0) {
        const float4 bias = *(const float4*)(b1 + ccol);
        acc0 = bias; acc1 = bias; acc2 = bias; acc3 = bias;
      }
      const int kb = kh * 64;
      for (int k = 0; k < 64; k += 4) {
        const float4 w0 = *(const float4*)(sW + (k + 0) * 64 + cg * 4);
        const float4 w1 = *(const float4*)(sW + (k + 1) * 64 + cg * 4);
        const float4 w2 = *(const float4*)(sW + (k + 2) * 64 + cg * 4);
        const float4 w3 = *(const float4*)(sW + (k + 3) * 64 + cg * 4);
        const float4 a0 = *(const float4*)(&sh[r0 + 0][kb + k]);
        const float4 a1 = *(const float4*)(&sh[r0 + 1][kb + k]);
        const float4 a2 = *(const float4*)(&sh[r0 + 2][kb + k]);
        const float4 a3 = *(const float4*)(&sh[r0 + 3][kb + k]);
        fma4(acc0, a0.x, w0); fma4(acc0, a0.y, w1); fma4(acc0, a0.z, w2); fma4(acc0, a0.w, w3);
        fma4(acc1, a1.x, w0); fma4(acc1, a1.y, w1); fma4(acc1, a1.z, w2); fma4(acc1, a1.w, w3);
        fma4(acc2, a2.x, w0); fma4(acc2, a2.y, w1); fma4(acc2, a2.z, w2); fma4(acc2, a2.w, w3);
        fma4(acc3, a3.x, w0); fma4(acc3, a3.y, w1); fma4(acc3, a3.z, w2); fma4(acc3, a3.w, w3);
      }
    }
    float4 ls = make_float4(0.f, 0.f, 0.f, 0.f);
    float4 lq = make_float4(0.f, 0.f, 0.f, 0.f);
    const float4* accs[4] = {&acc0, &acc1, &acc2, &acc3};
    for (int q = 0; q < 4; ++q) {
      const int gr = row0 + r0 + q;
      if (gr < NN) {
        const float4 a = *accs[q];
        *(float4*)(h1 + (size_t)gr * D + ccol) = a;
        ls.x += a.x; ls.y += a.y; ls.z += a.z; ls.w += a.w;
        lq.x += a.x * a.x; lq.y += a.y * a.y; lq.z += a.z * a.z; lq.w += a.w * a.w;
      }
    }
    atomicAdd(&ssum[ccol + 0], ls.x);
    atomicAdd(&ssum[ccol + 1], ls.y);
    atomicAdd(&ssum[ccol + 2], ls.z);
    atomicAdd(&ssum[ccol + 3], ls.w);
    atomicAdd(&ssq[ccol + 0], lq.x);
    atomicAdd(&ssq[ccol + 1], lq.y);
    atomicAdd(&ssq[ccol + 2], lq.z);
    atomicAdd(&ssq[ccol + 3], lq.w);
  }
  __syncthreads();
  if (tid < D) {
    atomicAdd(&gsum[tid], ssum[tid]);
    atomicAdd(&gsumsq[tid], ssq[tid]);
  }
}

// ---------------------------------------------------------------------------
// K4: out = relu(h1*A + B) @ W2 + b2, BN-finalize computed in-block
// (A = gamma*rsqrt(var+eps), B = beta - mean*A from gsum/gsumsq).
// ---------------------------------------------------------------------------
__global__ __launch_bounds__(256) void k_gemm2(const float* __restrict__ hbuf,
                                               const float* __restrict__ gsum,
                                               const float* __restrict__ gsq,
                                               const float* __restrict__ gamma,
                                               const float* __restrict__ beta,
                                               const float* __restrict__ W2,
                                               const float* __restrict__ b2,
                                               float* __restrict__ out) {
  __shared__ float sh[64][132];
  __shared__ float sW[64 * 64];
  __shared__ float sA[D];
  __shared__ float sB[D];

  const int tid = threadIdx.x;
  const int row0 = blockIdx.x * 64;

  if (tid < D) {
    const float invN = 1.0f / (float)NN;
    const float mean = gsum[tid] * invN;
    const float var = gsq[tid] * invN - mean * mean;
    const float A = gamma[tid] * rsqrtf(var + 1e-5f);
    sA[tid] = A;
    sB[tid] = beta[tid] - mean * A;
  }
  __syncthreads();

  for (int i = tid; i < 2048; i += 256) {
    const int r = i >> 5;
    const int c4 = (i & 31) << 2;
    const int gr = row0 + r;
    float4 v = make_float4(0.f, 0.f, 0.f, 0.f);
    if (gr < NN) {
      const float4 h = *(const float4*)(hbuf + (size_t)gr * D + c4);
      v.x = fmaxf(fmaf(h.x, sA[c4 + 0], sB[c4 + 0]), 0.f);
      v.y = fmaxf(fmaf(h.y, sA[c4 + 1], sB[c4 + 1]), 0.f);
      v.z = fmaxf(fmaf(h.z, sA[c4 + 2], sB[c4 + 2]), 0.f);
      v.w = fmaxf(fmaf(h.w, sA[c4 + 3], sB[c4 + 3]), 0.f);
    }
    *(float4*)(&sh[r][c4]) = v;
  }

  const int cg = tid & 15;
  const int rt = tid >> 4;
  const int r0 = rt * 4;

  for (int p = 0; p < 2; ++p) {
    const int ccol = p * 64 + cg * 4;
    float4 acc0, acc1, acc2, acc3;
    for (int kh = 0; kh < 2; ++kh) {
      __syncthreads();
      for (int i = tid; i < 1024; i += 256) {
        const int k = i >> 4;
        const int c4 = (i & 15) << 2;
        *(float4*)(sW + k * 64 + c4) =
            *(const float4*)(W2 + (size_t)(kh * 64 + k) * D + p * 64 + c4);
      }
      __syncthreads();
      if (kh == 0) {
        const float4 bias = *(const float4*)(b2 + ccol);
        acc0 = bias; acc1 = bias; acc2 = bias; acc3 = bias;
      }
      const int kb = kh * 64;
      for (int k = 0; k < 64; k += 4) {
        const float4 w0 = *(const float4*)(sW + (k + 0) * 64 + cg * 4);
        const float4 w1 = *(const float4*)(sW + (k + 1) * 64 + cg * 4);
        const float4 w2 = *(const float4*)(sW + (k + 2) * 64 + cg * 4);
        const float4 w3 = *(const float4*)(sW + (k + 3) * 64 + cg * 4);
        const float4 a0 = *(const float4*)(&sh[r0 + 0][kb + k]);
        const float4 a1 = *(const float4*)(&sh[r0 + 1][kb + k]);
        const float4 a2 = *(const float4*)(&sh[r0 + 2][kb + k]);
        const float4 a3 = *(const float4*)(&sh[r0 + 3][kb + k]);
        fma4(acc0, a0.x, w0); fma4(acc0, a0.y, w1); fma4(acc0, a0.z, w2); fma4(acc0, a0.w, w3);
        fma4(acc1, a1.x, w0); fma4(acc1, a1.y, w1); fma4(acc1, a1.z, w2); fma4(acc1, a1.w, w3);
        fma4(acc2, a2.x, w0); fma4(acc2, a2.y, w1); fma4(acc2, a2.z, w2); fma4(acc2, a2.w, w3);
        fma4(acc3, a3.x, w0); fma4(acc3, a3.y, w1); fma4(acc3, a3.z, w2); fma4(acc3, a3.w, w3);
      }
    }
    for (int q = 0; q < 4; ++q) {
      const int gr = row0 + r0 + q;
      if (gr < NN) {
        const float4* accs[4] = {&acc0, &acc1, &acc2, &acc3};
        *(float4*)(out + (size_t)gr * D + ccol) = *accs[q];
      }
    }
  }
}

extern "C" void kernel_launch(void* const* d_in, const int* in_sizes, int n_in,
                              void* d_out, int out_size, void* d_ws, size_t ws_size,
                              hipStream_t stream) {
  const float* x    = (const float*)d_in[0];
  const int* ea     = (const int*)d_in[1];
  const int* src    = (const int*)d_in[2];
  const int* dst    = (const int*)d_in[3];
  const float* bemb = (const float*)d_in[4];
  const float* epsp = (const float*)d_in[5];
  const float* W1   = (const float*)d_in[6];
  const float* b1   = (const float*)d_in[7];
  const float* gam  = (const float*)d_in[8];
  const float* bet  = (const float*)d_in[9];
  const float* W2   = (const float*)d_in[10];
  const float* b2   = (const float*)d_in[11];
  float* out = (float*)d_out;

  float* ws        = (float*)d_ws;
  float* hbuf      = ws;                                 // NN*D
  int* cnt         = (int*)(ws + (size_t)NN * D);        // NN    (zeroed)
  float* gsum      = ws + (size_t)NN * D + NN;           // 128   (zeroed)
  float* gsumsq    = gsum + D;                           // 128   (zeroed)
  float* ctab      = gsumsq + D;                         // 125*128
  unsigned* packed = (unsigned*)(ctab + 125 * D);        // NN*MAXDEG (16 MB)

  hipMemsetAsync(cnt, 0, (size_t)(NN + 2 * D) * sizeof(int), stream);

  k_scatter<<<(NE / 4 + 255) / 256, 256, 0, stream>>>(dst, src, ea, bemb, cnt, packed, ctab);
  k_agg<<<NN / 8, 256, 0, stream>>>(x, ctab, epsp, cnt, packed, hbuf);
  k_gemm1<<<(NN + 63) / 64, 256, 0, stream>>>(hbuf, W1, b1, hbuf, gsum, gsumsq);
  k_gemm2<<<(NN + 63) / 64, 256, 0, stream>>>(hbuf, gsum, gsumsq, gam, bet, W2, b2, out);
}